// Round 8
// baseline (381.231 us; speedup 1.0000x reference)
//
#include <hip/hip_runtime.h>
#include <hip/hip_bf16.h>

#define BB 4
#define TT 2048
#define DIM 512
#define NH 8
#define HD 64
#define NROW (BB*TT)   // 8192
#define BH (BB*NH)     // 32

typedef unsigned short u16;
typedef unsigned int u32;
typedef __attribute__((ext_vector_type(8))) short bf16x8;   // 8 bf16 = 4 VGPRs
typedef __attribute__((ext_vector_type(8))) unsigned short u16x8;
typedef __attribute__((ext_vector_type(4))) float f32x4;
typedef __attribute__((ext_vector_type(4))) unsigned short u16x4;

static __device__ __forceinline__ float bf2f(u16 u) {
    return __uint_as_float(((u32)u) << 16);
}
static __device__ __forceinline__ u16 f2bf(float f) {
    u32 u = __float_as_uint(f);
    u32 r = (u + 0x7FFFu + ((u >> 16) & 1u)) >> 16;
    return (u16)r;
}
// round-half-up pack of two f32 -> two bf16 in one u32 (cheap epilogue round)
static __device__ __forceinline__ u32 pk2bf(float a, float b) {
    u32 ua = (__float_as_uint(a) + 0x8000u) >> 16;
    u32 ub = (__float_as_uint(b) + 0x8000u) & 0xFFFF0000u;
    return ua | ub;
}

// ---------------- prep: fused convert_x (blocks 0..255) + W transposes
// (256..767 Wqkv, 768..1023 Wproj)
__global__ __launch_bounds__(256) void prep_kernel(
    const float* __restrict__ x, u16* __restrict__ x16, u32* __restrict__ bmaxsq,
    const float* __restrict__ Wqkv, u16* __restrict__ Wtq,
    const float* __restrict__ Wproj, u16* __restrict__ Wtp)
{
    const int bid = blockIdx.x;
    const int tid = threadIdx.x;
    __shared__ u16 t[32][33];
    __shared__ float red[4];

    if (bid < 256) {
        // convert x f32 -> bf16 + row ||x||^2 -> batch max (1 atomic/block)
        const int row = bid * 32 + (tid >> 3);
        const int b = (bid * 32) >> 11;
        const float* xr = x   + (size_t)row * DIM + (tid & 7) * 64;
        u16*        xo  = x16 + (size_t)row * DIM + (tid & 7) * 64;
        float s = 0.0f;
        #pragma unroll
        for (int j = 0; j < 8; ++j) {
            float4 a = *(const float4*)(xr + j*8);
            float4 c = *(const float4*)(xr + j*8 + 4);
            s += a.x*a.x + a.y*a.y + a.z*a.z + a.w*a.w;
            s += c.x*c.x + c.y*c.y + c.z*c.z + c.w*c.w;
            u16x8 pk;
            pk[0]=f2bf(a.x); pk[1]=f2bf(a.y); pk[2]=f2bf(a.z); pk[3]=f2bf(a.w);
            pk[4]=f2bf(c.x); pk[5]=f2bf(c.y); pk[6]=f2bf(c.z); pk[7]=f2bf(c.w);
            *(u16x8*)(xo + j*8) = pk;
        }
        #pragma unroll
        for (int off = 1; off < 8; off <<= 1) s += __shfl_xor(s, off, 64);
        float m = s;
        #pragma unroll
        for (int off = 8; off < 64; off <<= 1) m = fmaxf(m, __shfl_xor(m, off, 64));
        if ((tid & 63) == 0) red[tid >> 6] = m;
        __syncthreads();
        if (tid == 0) {
            float mx = fmaxf(fmaxf(red[0], red[1]), fmaxf(red[2], red[3]));
            atomicMax(&bmaxsq[b], __float_as_uint(mx));
        }
    } else {
        // convert-transpose W [K][N] f32 -> Wt [N][K] bf16
        const float* in; u16* outp; int K, N, tb;
        if (bid < 768) { in = Wqkv; outp = Wtq; K = 512; N = 1024; tb = bid - 256; }
        else           { in = Wproj; outp = Wtp; K = 512; N = 512;  tb = bid - 768; }
        const int ntiles = N >> 5;
        const int bx = tb % ntiles, by = tb / ntiles;
        const int n0 = bx * 32, k0 = by * 32;
        const int tx = tid & 31, ty = tid >> 5;
        #pragma unroll
        for (int i = 0; i < 32; i += 8)
            t[ty + i][tx] = f2bf(in[(size_t)(k0 + ty + i) * N + n0 + tx]);
        __syncthreads();
        #pragma unroll
        for (int i = 0; i < 32; i += 8)
            outp[(size_t)(n0 + ty + i) * K + k0 + tx] = t[tx][ty + i];
    }
}

// ---------------- MFMA GEMM: qkv = x16 @ Wqkv (via Wt [1024][512] bf16),
// scatter epilogue -> q bf16 [b,h,t,d], v bf16 [b,h,d,t].
#define LDG 72
__global__ __launch_bounds__(256) void qkv_mfma(
    const u16* __restrict__ x16, const u16* __restrict__ Wt,
    u16* __restrict__ q16, u16* __restrict__ vt16)
{
    const int tid = threadIdx.x, lane = tid & 63, w = tid >> 6;
    const int li = lane & 15, quad = lane >> 4;
    const int mb = blockIdx.x >> 3, nb = blockIdx.x & 7;   // 64 x 8
    const int row0 = mb * 128, n0 = nb * 128;
    const int b = row0 >> 11;
    const int wm = w >> 1, wn = w & 1;

    __shared__ __align__(16) u16 as[128 * LDG];
    __shared__ __align__(16) u16 bs[128 * LDG];

    f32x4 acc[4][4];
    #pragma unroll
    for (int mi = 0; mi < 4; ++mi)
        #pragma unroll
        for (int ni = 0; ni < 4; ++ni) acc[mi][ni] = f32x4{0.f,0.f,0.f,0.f};

    for (int k0 = 0; k0 < DIM; k0 += 64) {
        __syncthreads();
        #pragma unroll
        for (int it = 0; it < 4; ++it) {
            int id = it * 256 + tid;          // 1024 chunks of 8 elems
            int r = id >> 3, c = id & 7;
            *(bf16x8*)&as[r*LDG + c*8] =
                *(const bf16x8*)(x16 + (size_t)(row0 + r)*DIM + k0 + c*8);
            *(bf16x8*)&bs[r*LDG + c*8] =
                *(const bf16x8*)(Wt  + (size_t)(n0  + r)*DIM + k0 + c*8);
        }
        __syncthreads();

        bf16x8 af[4][2], bfr[4][2];
        #pragma unroll
        for (int mi = 0; mi < 4; ++mi) {
            const u16* p = &as[(wm*64 + mi*16 + li)*LDG + quad*8];
            af[mi][0] = *(const bf16x8*)p;
            af[mi][1] = *(const bf16x8*)(p + 32);
        }
        #pragma unroll
        for (int ni = 0; ni < 4; ++ni) {
            const u16* p = &bs[(wn*64 + ni*16 + li)*LDG + quad*8];
            bfr[ni][0] = *(const bf16x8*)p;
            bfr[ni][1] = *(const bf16x8*)(p + 32);
        }
        #pragma unroll
        for (int mi = 0; mi < 4; ++mi)
            #pragma unroll
            for (int ni = 0; ni < 4; ++ni) {
                acc[mi][ni] = __builtin_amdgcn_mfma_f32_16x16x32_bf16(
                    af[mi][0], bfr[ni][0], acc[mi][ni], 0, 0, 0);
                acc[mi][ni] = __builtin_amdgcn_mfma_f32_16x16x32_bf16(
                    af[mi][1], bfr[ni][1], acc[mi][ni], 0, 0, 0);
            }
    }

    // epilogue scatter: col = d*16 + kk*8 + h; 16-col tile => constant d
    const int h = li & 7;
    const bool isv = ((li >> 3) & 1) != 0;
    #pragma unroll
    for (int ni = 0; ni < 4; ++ni) {
        int col0 = n0 + wn*64 + ni*16;
        int d = col0 >> 4;
        #pragma unroll
        for (int mi = 0; mi < 4; ++mi) {
            int t0 = (row0 & (TT-1)) + wm*64 + mi*16 + quad*4;
            if (!isv) {
                u16* dst = q16 + ((size_t)(b*NH + h)*TT + t0)*HD + d;
                #pragma unroll
                for (int r = 0; r < 4; ++r)
                    dst[(size_t)r * HD] = f2bf(acc[mi][ni][r]);
            } else {
                u16x4 pk;
                pk.x = f2bf(acc[mi][ni][0]); pk.y = f2bf(acc[mi][ni][1]);
                pk.z = f2bf(acc[mi][ni][2]); pk.w = f2bf(acc[mi][ni][3]);
                *(u16x4*)(vt16 + ((size_t)(b*NH + h)*HD + d)*TT + t0) = pk;
            }
        }
    }
}

// ---------------- MFMA GEMM: out(f32) = ao16 @ Wproj + bias(f32)
__global__ __launch_bounds__(256) void proj_mfma(
    const u16* __restrict__ ao16, const u16* __restrict__ Wt,
    const float* __restrict__ bp, float* __restrict__ out)
{
    const int tid = threadIdx.x, lane = tid & 63, w = tid >> 6;
    const int li = lane & 15, quad = lane >> 4;
    const int mb = blockIdx.x >> 2, nb = blockIdx.x & 3;   // 64 x 4
    const int row0 = mb * 128, n0 = nb * 128;
    const int wm = w >> 1, wn = w & 1;

    __shared__ __align__(16) u16 as[128 * LDG];
    __shared__ __align__(16) u16 bs[128 * LDG];

    f32x4 acc[4][4];
    #pragma unroll
    for (int mi = 0; mi < 4; ++mi)
        #pragma unroll
        for (int ni = 0; ni < 4; ++ni) acc[mi][ni] = f32x4{0.f,0.f,0.f,0.f};

    for (int k0 = 0; k0 < DIM; k0 += 64) {
        __syncthreads();
        #pragma unroll
        for (int it = 0; it < 4; ++it) {
            int id = it * 256 + tid;
            int r = id >> 3, c = id & 7;
            *(bf16x8*)&as[r*LDG + c*8] =
                *(const bf16x8*)(ao16 + (size_t)(row0 + r)*DIM + k0 + c*8);
            *(bf16x8*)&bs[r*LDG + c*8] =
                *(const bf16x8*)(Wt   + (size_t)(n0  + r)*DIM + k0 + c*8);
        }
        __syncthreads();

        bf16x8 af[4][2], bfr[4][2];
        #pragma unroll
        for (int mi = 0; mi < 4; ++mi) {
            const u16* p = &as[(wm*64 + mi*16 + li)*LDG + quad*8];
            af[mi][0] = *(const bf16x8*)p;
            af[mi][1] = *(const bf16x8*)(p + 32);
        }
        #pragma unroll
        for (int ni = 0; ni < 4; ++ni) {
            const u16* p = &bs[(wn*64 + ni*16 + li)*LDG + quad*8];
            bfr[ni][0] = *(const bf16x8*)p;
            bfr[ni][1] = *(const bf16x8*)(p + 32);
        }
        #pragma unroll
        for (int mi = 0; mi < 4; ++mi)
            #pragma unroll
            for (int ni = 0; ni < 4; ++ni) {
                acc[mi][ni] = __builtin_amdgcn_mfma_f32_16x16x32_bf16(
                    af[mi][0], bfr[ni][0], acc[mi][ni], 0, 0, 0);
                acc[mi][ni] = __builtin_amdgcn_mfma_f32_16x16x32_bf16(
                    af[mi][1], bfr[ni][1], acc[mi][ni], 0, 0, 0);
            }
    }

    #pragma unroll
    for (int ni = 0; ni < 4; ++ni) {
        int col = n0 + wn*64 + ni*16 + li;
        float bias = bp[col];
        #pragma unroll
        for (int mi = 0; mi < 4; ++mi) {
            int r0 = row0 + wm*64 + mi*16 + quad*4;
            #pragma unroll
            for (int r = 0; r < 4; ++r)
                out[(size_t)(r0 + r)*DIM + col] = acc[mi][ni][r] + bias;
        }
    }
}

// ---------------- qsq: qsq[b,h,t] = sum_d q^2 ; asq[b,h] via 1 atomic/block
__global__ __launch_bounds__(256) void qsq_kernel(
    const u16* __restrict__ q16, float* __restrict__ qsq, float* __restrict__ asq)
{
    const int tid = threadIdx.x;
    const int bh = blockIdx.x >> 3;
    const int r0 = (blockIdx.x & 7) * 256;
    const u16* qb = q16 + ((size_t)bh * TT + r0) * HD;

    float tot = 0.0f;
    #pragma unroll
    for (int i = 0; i < 8; ++i) {
        int row = i * 32 + (tid >> 3);
        u16x8 v = *(const u16x8*)(qb + (size_t)row * HD + (tid & 7) * 8);
        float s = 0.0f;
        #pragma unroll
        for (int j = 0; j < 8; ++j) { float f = bf2f(v[j]); s += f * f; }
        tot += s;
        #pragma unroll
        for (int off = 1; off < 8; off <<= 1) s += __shfl_xor(s, off, 64);
        if ((tid & 7) == 0) qsq[(size_t)bh * TT + r0 + row] = s;
    }
    __shared__ float red[4];
    #pragma unroll
    for (int off = 32; off > 0; off >>= 1) tot += __shfl_down(tot, off, 64);
    if ((tid & 63) == 0) red[tid >> 6] = tot;
    __syncthreads();
    if (tid == 0) atomicAdd(&asq[bh], red[0] + red[1] + red[2] + red[3]);
}

// ---------------- attention v3: barrier-free, S^T operand order, fragment
// loads direct from global (L1/L2-resident K,V), wave-private P in LDS.
// score max known analytically (=0 shifted) -> no online softmax.
#define LDP 72
__global__ __launch_bounds__(256) void attn_kernel(
    const u16* __restrict__ q16, const u16* __restrict__ vt16,
    const float* __restrict__ qsq, const float* __restrict__ asq,
    const u32* __restrict__ bmaxsq, u16* __restrict__ ao16)
{
    const int tid = threadIdx.x;
    const int lane = tid & 63, w = tid >> 6;
    const int li = lane & 15, quad = lane >> 4;
    const int bh = blockIdx.x >> 5;
    const int qtile = blockIdx.x & 31;
    const int b = bh >> 3, h = bh & 7;

    __shared__ __align__(16) u16 ps[4][16 * LDP];   // per-wave P [t][s]

    const u16* qg = q16  + (size_t)bh * TT * HD;    // [t][d]
    const u16* vg = vt16 + (size_t)bh * HD * TT;    // [d][t]
    const float* qsqg = qsq + (size_t)bh * TT;

    float cf;   // 100 * log2(e) / (a * bmax + eps)
    {
        float a  = sqrtf(asq[bh]);
        float bm = sqrtf(__uint_as_float(bmaxsq[b]));
        cf = (100.0f * 1.44269504089f) / (a * bm + 1e-10f);
    }
    const float c2 = 2.0f * cf;

    const int qt0w = qtile * 64 + w * 16;
    {
    }
    const u16* qr = qg + (size_t)(qt0w + li) * HD + quad * 8;
    bf16x8 a0 = *(const bf16x8*)qr;        // Q B-frag rows t, k=0..31
    bf16x8 a1 = *(const bf16x8*)(qr + 32); // k=32..63

    const float sqt = cf * qsqg[qt0w + li];   // this lane's t-term (t = li col)

    // loop-invariant lane offsets
    int koff[4];
    #pragma unroll
    for (int cj = 0; cj < 4; ++cj) koff[cj] = (cj*16 + li)*HD + quad*8;
    int voff[2][4];
    #pragma unroll
    for (int kj = 0; kj < 2; ++kj)
        #pragma unroll
        for (int dj = 0; dj < 4; ++dj)
            voff[kj][dj] = (dj*16 + li)*TT + kj*32 + quad*8;
    const int qsoff = li*LDP;   // ps row for this lane's t

    u16* psw = &ps[w][0];

    float ssum = 0.0f;           // partial softmax denom for t = qt0w + li
    f32x4 oacc[4];
    #pragma unroll
    for (int dj = 0; dj < 4; ++dj) oacc[dj] = f32x4{0.f, 0.f, 0.f, 0.f};

    const u16* kbase = qg;
    const u16* vbase = vg;
    const float* qsb = qsqg;

    for (int s0 = 0; s0 < TT; s0 += 64) {
        // ---- S^T = K Q^T : lane holds rows s=quad*4+r (+cj*16), col t=li
        #pragma unroll
        for (int cj = 0; cj < 4; ++cj) {
            const u16* kr = kbase + koff[cj];
            bf16x8 k0 = *(const bf16x8*)kr;
            bf16x8 k1 = *(const bf16x8*)(kr + 32);
            f32x4 acc = f32x4{0.f, 0.f, 0.f, 0.f};
            acc = __builtin_amdgcn_mfma_f32_16x16x32_bf16(k0, a0, acc, 0, 0, 0);
            acc = __builtin_amdgcn_mfma_f32_16x16x32_bf16(k1, a1, acc, 0, 0, 0);
            f32x4 q4 = *(const f32x4*)(qsb + cj*16 + quad*4);
            float p0 = exp2f(c2*acc[0] - fmaf(cf, q4[0], sqt));
            float p1 = exp2f(c2*acc[1] - fmaf(cf, q4[1], sqt));
            float p2 = exp2f(c2*acc[2] - fmaf(cf, q4[2], sqt));
            float p3 = exp2f(c2*acc[3] - fmaf(cf, q4[3], sqt));
            ssum += (p0 + p1) + (p2 + p3);
            uint2 pk;
            pk.x = pk2bf(p0, p1);
            pk.y = pk2bf(p2, p3);
            *(uint2*)&psw[qsoff + cj*16 + quad*4] = pk;   // P[t=li][4 consec s]
        }
        // ---- O += P V : A = ps rows t, B = V^T rows d (direct global)
        #pragma unroll
        for (int kj = 0; kj < 2; ++kj) {
            bf16x8 ap = *(const bf16x8*)&psw[qsoff + kj*32 + quad*8];
            #pragma unroll
            for (int dj = 0; dj < 4; ++dj) {
                bf16x8 bv = *(const bf16x8*)(vbase + voff[kj][dj]);
                oacc[dj] = __builtin_amdgcn_mfma_f32_16x16x32_bf16(
                    ap, bv, oacc[dj], 0, 0, 0);
            }
        }
        kbase += 64 * HD;
        vbase += 64;
        qsb   += 64;
    }

    // full denom for t=li: reduce across the 4 quads holding the same li
    ssum += __shfl_xor(ssum, 16, 64);
    ssum += __shfl_xor(ssum, 32, 64);

    // redistribute to output layout rows t = qt0w + quad*4 + r
    float inv[4];
    #pragma unroll
    for (int r = 0; r < 4; ++r)
        inv[r] = 1.0f / __shfl(ssum, quad*4 + r, 64);

    #pragma unroll
    for (int dj = 0; dj < 4; ++dj)
        #pragma unroll
        for (int r = 0; r < 4; ++r) {
            int t = qt0w + quad*4 + r;
            ao16[((size_t)(b*TT + t))*DIM + h*HD + dj*16 + li] =
                f2bf(oacc[dj][r] * inv[r]);
        }
}

extern "C" void kernel_launch(void* const* d_in, const int* in_sizes, int n_in,
                              void* d_out, int out_size, void* d_ws, size_t ws_size,
                              hipStream_t stream)
{
    const float* x     = (const float*)d_in[0];   // [4,2048,512] f32
    const float* Wqkv  = (const float*)d_in[1];   // [512,1024]  f32
    const float* Wproj = (const float*)d_in[2];   // [512,512]   f32
    const float* bproj = (const float*)d_in[3];   // [512]       f32
    float* out = (float*)d_out;                   // [4,2048,512] f32

    char* ws = (char*)d_ws;
    const size_t MB = 1024*1024;
    u16*   q16  = (u16*)(ws);                          // 8 MB  [b,h,t,d] bf16
    u16*   vt16 = (u16*)(ws + 8*MB);                   // 8 MB  [b,h,d,t] bf16
    u16*   ao16 = (u16*)(ws + 16*MB);                  // 8 MB  [b,t,dim] bf16
    u16*   x16  = (u16*)(ws + 24*MB);                  // 8 MB  [b,t,dim] bf16
    u16*   Wtq  = (u16*)(ws + 32*MB);                  // 1 MB  [1024][512]
    u16*   Wtp  = (u16*)(ws + 33*MB);                  // 0.5MB [512][512]
    float* qsq  = (float*)(ws + 34*MB);                // 256 KB (16B aligned)
    float* asq  = (float*)(ws + 34*MB + 262144);       // 128 B
    u32* bmaxsq = (u32*)(ws + 34*MB + 262144 + 128);   // 16 B

    (void)in_sizes; (void)n_in; (void)out_size; (void)ws_size;

    // zero asq + bmaxsq (adjacent, 144 B) -- graph-capture-safe async memset
    hipMemsetAsync(ws + 34*MB + 262144, 0, 144, stream);

    prep_kernel<<<1024, 256, 0, stream>>>(x, x16, bmaxsq, Wqkv, Wtq, Wproj, Wtp);

    qkv_mfma<<<64*8, 256, 0, stream>>>(x16, Wtq, q16, vt16);

    qsq_kernel<<<BH*8, 256, 0, stream>>>(q16, qsq, asq);

    attn_kernel<<<BH*32, 256, 0, stream>>>(q16, vt16, qsq, asq, bmaxsq, ao16);

    proj_mfma<<<64*4, 256, 0, stream>>>(ao16, Wtp, bproj, out);
}

// Round 9
// 258.159 us; speedup vs baseline: 1.4767x; 1.4767x over previous
//
#include <hip/hip_runtime.h>
#include <hip/hip_bf16.h>

#define BB 4
#define TT 2048
#define DIM 512
#define NH 8
#define HD 64
#define NROW (BB*TT)   // 8192
#define BH (BB*NH)     // 32

typedef unsigned short u16;
typedef unsigned int u32;
typedef __attribute__((ext_vector_type(8))) short bf16x8;   // 8 bf16 = 4 VGPRs
typedef __attribute__((ext_vector_type(8))) unsigned short u16x8;
typedef __attribute__((ext_vector_type(4))) float f32x4;
typedef __attribute__((ext_vector_type(4))) unsigned short u16x4;

static __device__ __forceinline__ float bf2f(u16 u) {
    return __uint_as_float(((u32)u) << 16);
}
static __device__ __forceinline__ u16 f2bf(float f) {
    u32 u = __float_as_uint(f);
    u32 r = (u + 0x7FFFu + ((u >> 16) & 1u)) >> 16;
    return (u16)r;
}
// round-half-up pack of two f32 -> two bf16 in one u32
static __device__ __forceinline__ u32 pk2bf(float a, float b) {
    u32 ua = (__float_as_uint(a) + 0x8000u) >> 16;
    u32 ub = (__float_as_uint(b) + 0x8000u) & 0xFFFF0000u;
    return ua | ub;
}

// ---------------- prep: fused convert_x (blocks 0..255) + W transposes
__global__ __launch_bounds__(256) void prep_kernel(
    const float* __restrict__ x, u16* __restrict__ x16, u32* __restrict__ bmaxsq,
    const float* __restrict__ Wqkv, u16* __restrict__ Wtq,
    const float* __restrict__ Wproj, u16* __restrict__ Wtp)
{
    const int bid = blockIdx.x;
    const int tid = threadIdx.x;
    __shared__ u16 t[32][33];
    __shared__ float red[4];

    if (bid < 256) {
        const int row = bid * 32 + (tid >> 3);
        const int b = (bid * 32) >> 11;
        const float* xr = x   + (size_t)row * DIM + (tid & 7) * 64;
        u16*        xo  = x16 + (size_t)row * DIM + (tid & 7) * 64;
        float s = 0.0f;
        #pragma unroll
        for (int j = 0; j < 8; ++j) {
            float4 a = *(const float4*)(xr + j*8);
            float4 c = *(const float4*)(xr + j*8 + 4);
            s += a.x*a.x + a.y*a.y + a.z*a.z + a.w*a.w;
            s += c.x*c.x + c.y*c.y + c.z*c.z + c.w*c.w;
            u16x8 pk;
            pk[0]=f2bf(a.x); pk[1]=f2bf(a.y); pk[2]=f2bf(a.z); pk[3]=f2bf(a.w);
            pk[4]=f2bf(c.x); pk[5]=f2bf(c.y); pk[6]=f2bf(c.z); pk[7]=f2bf(c.w);
            *(u16x8*)(xo + j*8) = pk;
        }
        #pragma unroll
        for (int off = 1; off < 8; off <<= 1) s += __shfl_xor(s, off, 64);
        float m = s;
        #pragma unroll
        for (int off = 8; off < 64; off <<= 1) m = fmaxf(m, __shfl_xor(m, off, 64));
        if ((tid & 63) == 0) red[tid >> 6] = m;
        __syncthreads();
        if (tid == 0) {
            float mx = fmaxf(fmaxf(red[0], red[1]), fmaxf(red[2], red[3]));
            atomicMax(&bmaxsq[b], __float_as_uint(mx));
        }
    } else {
        const float* in; u16* outp; int K, N, tb;
        if (bid < 768) { in = Wqkv; outp = Wtq; K = 512; N = 1024; tb = bid - 256; }
        else           { in = Wproj; outp = Wtp; K = 512; N = 512;  tb = bid - 768; }
        const int ntiles = N >> 5;
        const int bx = tb % ntiles, by = tb / ntiles;
        const int n0 = bx * 32, k0 = by * 32;
        const int tx = tid & 31, ty = tid >> 5;
        #pragma unroll
        for (int i = 0; i < 32; i += 8)
            t[ty + i][tx] = f2bf(in[(size_t)(k0 + ty + i) * N + n0 + tx]);
        __syncthreads();
        #pragma unroll
        for (int i = 0; i < 32; i += 8)
            outp[(size_t)(n0 + ty + i) * K + k0 + tx] = t[tx][ty + i];
    }
}

// ---------------- MFMA GEMM: qkv = x16 @ Wqkv (via Wt [1024][512] bf16)
#define LDG 72
__global__ __launch_bounds__(256) void qkv_mfma(
    const u16* __restrict__ x16, const u16* __restrict__ Wt,
    u16* __restrict__ q16, u16* __restrict__ vt16)
{
    const int tid = threadIdx.x, lane = tid & 63, w = tid >> 6;
    const int li = lane & 15, quad = lane >> 4;
    const int mb = blockIdx.x >> 3, nb = blockIdx.x & 7;   // 64 x 8
    const int row0 = mb * 128, n0 = nb * 128;
    const int b = row0 >> 11;
    const int wm = w >> 1, wn = w & 1;

    __shared__ __align__(16) u16 as[128 * LDG];
    __shared__ __align__(16) u16 bs[128 * LDG];

    f32x4 acc[4][4];
    #pragma unroll
    for (int mi = 0; mi < 4; ++mi)
        #pragma unroll
        for (int ni = 0; ni < 4; ++ni) acc[mi][ni] = f32x4{0.f,0.f,0.f,0.f};

    for (int k0 = 0; k0 < DIM; k0 += 64) {
        __syncthreads();
        #pragma unroll
        for (int it = 0; it < 4; ++it) {
            int id = it * 256 + tid;
            int r = id >> 3, c = id & 7;
            *(bf16x8*)&as[r*LDG + c*8] =
                *(const bf16x8*)(x16 + (size_t)(row0 + r)*DIM + k0 + c*8);
            *(bf16x8*)&bs[r*LDG + c*8] =
                *(const bf16x8*)(Wt  + (size_t)(n0  + r)*DIM + k0 + c*8);
        }
        __syncthreads();

        bf16x8 af[4][2], bfr[4][2];
        #pragma unroll
        for (int mi = 0; mi < 4; ++mi) {
            const u16* p = &as[(wm*64 + mi*16 + li)*LDG + quad*8];
            af[mi][0] = *(const bf16x8*)p;
            af[mi][1] = *(const bf16x8*)(p + 32);
        }
        #pragma unroll
        for (int ni = 0; ni < 4; ++ni) {
            const u16* p = &bs[(wn*64 + ni*16 + li)*LDG + quad*8];
            bfr[ni][0] = *(const bf16x8*)p;
            bfr[ni][1] = *(const bf16x8*)(p + 32);
        }
        #pragma unroll
        for (int mi = 0; mi < 4; ++mi)
            #pragma unroll
            for (int ni = 0; ni < 4; ++ni) {
                acc[mi][ni] = __builtin_amdgcn_mfma_f32_16x16x32_bf16(
                    af[mi][0], bfr[ni][0], acc[mi][ni], 0, 0, 0);
                acc[mi][ni] = __builtin_amdgcn_mfma_f32_16x16x32_bf16(
                    af[mi][1], bfr[ni][1], acc[mi][ni], 0, 0, 0);
            }
    }

    const int h = li & 7;
    const bool isv = ((li >> 3) & 1) != 0;
    #pragma unroll
    for (int ni = 0; ni < 4; ++ni) {
        int col0 = n0 + wn*64 + ni*16;
        int d = col0 >> 4;
        #pragma unroll
        for (int mi = 0; mi < 4; ++mi) {
            int t0 = (row0 & (TT-1)) + wm*64 + mi*16 + quad*4;
            if (!isv) {
                u16* dst = q16 + ((size_t)(b*NH + h)*TT + t0)*HD + d;
                #pragma unroll
                for (int r = 0; r < 4; ++r)
                    dst[(size_t)r * HD] = f2bf(acc[mi][ni][r]);
            } else {
                u16x4 pk;
                pk.x = f2bf(acc[mi][ni][0]); pk.y = f2bf(acc[mi][ni][1]);
                pk.z = f2bf(acc[mi][ni][2]); pk.w = f2bf(acc[mi][ni][3]);
                *(u16x4*)(vt16 + ((size_t)(b*NH + h)*HD + d)*TT + t0) = pk;
            }
        }
    }
}

// ---------------- MFMA GEMM: out(f32) = ao16 @ Wproj + bias(f32)
__global__ __launch_bounds__(256) void proj_mfma(
    const u16* __restrict__ ao16, const u16* __restrict__ Wt,
    const float* __restrict__ bp, float* __restrict__ out)
{
    const int tid = threadIdx.x, lane = tid & 63, w = tid >> 6;
    const int li = lane & 15, quad = lane >> 4;
    const int mb = blockIdx.x >> 2, nb = blockIdx.x & 3;   // 64 x 4
    const int row0 = mb * 128, n0 = nb * 128;
    const int wm = w >> 1, wn = w & 1;

    __shared__ __align__(16) u16 as[128 * LDG];
    __shared__ __align__(16) u16 bs[128 * LDG];

    f32x4 acc[4][4];
    #pragma unroll
    for (int mi = 0; mi < 4; ++mi)
        #pragma unroll
        for (int ni = 0; ni < 4; ++ni) acc[mi][ni] = f32x4{0.f,0.f,0.f,0.f};

    for (int k0 = 0; k0 < DIM; k0 += 64) {
        __syncthreads();
        #pragma unroll
        for (int it = 0; it < 4; ++it) {
            int id = it * 256 + tid;
            int r = id >> 3, c = id & 7;
            *(bf16x8*)&as[r*LDG + c*8] =
                *(const bf16x8*)(ao16 + (size_t)(row0 + r)*DIM + k0 + c*8);
            *(bf16x8*)&bs[r*LDG + c*8] =
                *(const bf16x8*)(Wt   + (size_t)(n0  + r)*DIM + k0 + c*8);
        }
        __syncthreads();

        bf16x8 af[4][2], bfr[4][2];
        #pragma unroll
        for (int mi = 0; mi < 4; ++mi) {
            const u16* p = &as[(wm*64 + mi*16 + li)*LDG + quad*8];
            af[mi][0] = *(const bf16x8*)p;
            af[mi][1] = *(const bf16x8*)(p + 32);
        }
        #pragma unroll
        for (int ni = 0; ni < 4; ++ni) {
            const u16* p = &bs[(wn*64 + ni*16 + li)*LDG + quad*8];
            bfr[ni][0] = *(const bf16x8*)p;
            bfr[ni][1] = *(const bf16x8*)(p + 32);
        }
        #pragma unroll
        for (int mi = 0; mi < 4; ++mi)
            #pragma unroll
            for (int ni = 0; ni < 4; ++ni) {
                acc[mi][ni] = __builtin_amdgcn_mfma_f32_16x16x32_bf16(
                    af[mi][0], bfr[ni][0], acc[mi][ni], 0, 0, 0);
                acc[mi][ni] = __builtin_amdgcn_mfma_f32_16x16x32_bf16(
                    af[mi][1], bfr[ni][1], acc[mi][ni], 0, 0, 0);
            }
    }

    #pragma unroll
    for (int ni = 0; ni < 4; ++ni) {
        int col = n0 + wn*64 + ni*16 + li;
        float bias = bp[col];
        #pragma unroll
        for (int mi = 0; mi < 4; ++mi) {
            int r0 = row0 + wm*64 + mi*16 + quad*4;
            #pragma unroll
            for (int r = 0; r < 4; ++r)
                out[(size_t)(r0 + r)*DIM + col] = acc[mi][ni][r] + bias;
        }
    }
}

// ---------------- qsq: qsq[b,h,t] = sum_d q^2 ; asq[b,h] via 1 atomic/block
__global__ __launch_bounds__(256) void qsq_kernel(
    const u16* __restrict__ q16, float* __restrict__ qsq, float* __restrict__ asq)
{
    const int tid = threadIdx.x;
    const int bh = blockIdx.x >> 3;
    const int r0 = (blockIdx.x & 7) * 256;
    const u16* qb = q16 + ((size_t)bh * TT + r0) * HD;

    float tot = 0.0f;
    #pragma unroll
    for (int i = 0; i < 8; ++i) {
        int row = i * 32 + (tid >> 3);
        u16x8 v = *(const u16x8*)(qb + (size_t)row * HD + (tid & 7) * 8);
        float s = 0.0f;
        #pragma unroll
        for (int j = 0; j < 8; ++j) { float f = bf2f(v[j]); s += f * f; }
        tot += s;
        #pragma unroll
        for (int off = 1; off < 8; off <<= 1) s += __shfl_xor(s, off, 64);
        if ((tid & 7) == 0) qsq[(size_t)bh * TT + r0 + row] = s;
    }
    __shared__ float red[4];
    #pragma unroll
    for (int off = 32; off > 0; off >>= 1) tot += __shfl_down(tot, off, 64);
    if ((tid & 63) == 0) red[tid >> 6] = tot;
    __syncthreads();
    if (tid == 0) atomicAdd(&asq[bh], red[0] + red[1] + red[2] + red[3]);
}

// ---------------- attention v4: LDS-staged K/V (r7 structure) + S^T operand
// order (b64 P-writes) + 32 q-rows/wave (2 subtiles, 2x staged-data reuse).
// Known-max softmax in exp2 domain (row max analytically 0 after shift).
#define LDK 72
#define LDP 72
__global__ __launch_bounds__(256) void attn_kernel(
    const u16* __restrict__ q16, const u16* __restrict__ vt16,
    const float* __restrict__ qsq, const float* __restrict__ asq,
    const u32* __restrict__ bmaxsq, u16* __restrict__ ao16)
{
    const int tid = threadIdx.x;
    const int lane = tid & 63, w = tid >> 6;
    const int li = lane & 15, quad = lane >> 4;
    const int bh = blockIdx.x >> 4;       // 32
    const int qtile = blockIdx.x & 15;    // 16 tiles of 128 q-rows
    const int b = bh >> 3, h = bh & 7;

    __shared__ __align__(16) u16 ks[64 * LDK];      // K tile  [s][d]
    __shared__ __align__(16) u16 vt[64 * LDK];      // V^T tile [d][s]
    __shared__ __align__(16) u16 ps[4][32 * LDP];   // per-wave P [t][s]

    const u16* qg = q16  + (size_t)bh * TT * HD;    // [t][d]
    const u16* vg = vt16 + (size_t)bh * HD * TT;    // [d][t]
    const float* qsqg = qsq + (size_t)bh * TT;

    float cf;   // 100 * log2(e) / (a * bmax + eps)
    {
        float a  = sqrtf(asq[bh]);
        float bm = sqrtf(__uint_as_float(bmaxsq[b]));
        cf = (100.0f * 1.44269504089f) / (a * bm + 1e-10f);
    }
    const float c2 = 2.0f * cf;

    const int qt0w = qtile * 128 + w * 32;
    // Q B-frags for 2 subtiles (held in regs whole kernel); lane t-col = li
    bf16x8 a[2][2];
    float sqt[2];
    #pragma unroll
    for (int mi = 0; mi < 2; ++mi) {
        const u16* qr = qg + (size_t)(qt0w + mi*16 + li) * HD + quad * 8;
        a[mi][0] = *(const bf16x8*)qr;
        a[mi][1] = *(const bf16x8*)(qr + 32);
        sqt[mi] = cf * qsqg[qt0w + mi*16 + li];
    }

    u16* psw = &ps[w][0];
    float ssum[2] = {0.f, 0.f};
    f32x4 oacc[2][4];
    #pragma unroll
    for (int mi = 0; mi < 2; ++mi)
        #pragma unroll
        for (int dj = 0; dj < 4; ++dj) oacc[mi][dj] = f32x4{0.f, 0.f, 0.f, 0.f};

    for (int s0 = 0; s0 < TT; s0 += 64) {
        __syncthreads();   // prev tile's reads complete
        #pragma unroll
        for (int it = 0; it < 2; ++it) {
            int u = it * 256 + tid;        // 512 chunks of 8 elems
            int r = u >> 3, c = u & 7;
            *(bf16x8*)&ks[r*LDK + c*8] =
                *(const bf16x8*)(qg + (size_t)(s0 + r)*HD + c*8);
            *(bf16x8*)&vt[r*LDK + c*8] =
                *(const bf16x8*)(vg + (size_t)r*TT + s0 + c*8);
        }
        __syncthreads();   // staging visible

        // ---- S^T = K Q^T : lane holds s-rows quad*4+r (+cj*16), t-col li.
        // K frag read once per cj, reused by both subtiles.
        #pragma unroll
        for (int cj = 0; cj < 4; ++cj) {
            const u16* kr = &ks[(cj*16 + li)*LDK + quad*8];
            bf16x8 k0 = *(const bf16x8*)kr;
            bf16x8 k1 = *(const bf16x8*)(kr + 32);
            f32x4 q4 = *(const f32x4*)(qsqg + s0 + cj*16 + quad*4);
            #pragma unroll
            for (int mi = 0; mi < 2; ++mi) {
                f32x4 acc = f32x4{0.f, 0.f, 0.f, 0.f};
                acc = __builtin_amdgcn_mfma_f32_16x16x32_bf16(k0, a[mi][0], acc, 0, 0, 0);
                acc = __builtin_amdgcn_mfma_f32_16x16x32_bf16(k1, a[mi][1], acc, 0, 0, 0);
                float p0 = exp2f(c2*acc[0] - fmaf(cf, q4[0], sqt[mi]));
                float p1 = exp2f(c2*acc[1] - fmaf(cf, q4[1], sqt[mi]));
                float p2 = exp2f(c2*acc[2] - fmaf(cf, q4[2], sqt[mi]));
                float p3 = exp2f(c2*acc[3] - fmaf(cf, q4[3], sqt[mi]));
                ssum[mi] += (p0 + p1) + (p2 + p3);
                uint2 pk;
                pk.x = pk2bf(p0, p1);
                pk.y = pk2bf(p2, p3);
                *(uint2*)&psw[(mi*16 + li)*LDP + cj*16 + quad*4] = pk;
            }
        }

        // ---- O += P V : A = P rows t (wave-private LDS), B = V^T rows d.
        // V frags read once per (kj,dj), reused by both subtiles.
        #pragma unroll
        for (int kj = 0; kj < 2; ++kj) {
            bf16x8 bv[4];
            #pragma unroll
            for (int dj = 0; dj < 4; ++dj)
                bv[dj] = *(const bf16x8*)&vt[(dj*16 + li)*LDK + kj*32 + quad*8];
            #pragma unroll
            for (int mi = 0; mi < 2; ++mi) {
                bf16x8 ap = *(const bf16x8*)&psw[(mi*16 + li)*LDP + kj*32 + quad*8];
                #pragma unroll
                for (int dj = 0; dj < 4; ++dj)
                    oacc[mi][dj] = __builtin_amdgcn_mfma_f32_16x16x32_bf16(
                        ap, bv[dj], oacc[mi][dj], 0, 0, 0);
            }
        }
    }

    // denom: reduce quad-partials (lane li holds t=...+li), then redistribute
    #pragma unroll
    for (int mi = 0; mi < 2; ++mi) {
        ssum[mi] += __shfl_xor(ssum[mi], 16, 64);
        ssum[mi] += __shfl_xor(ssum[mi], 32, 64);
    }
    float inv[2][4];
    #pragma unroll
    for (int mi = 0; mi < 2; ++mi)
        #pragma unroll
        for (int r = 0; r < 4; ++r)
            inv[mi][r] = 1.0f / __shfl(ssum[mi], quad*4 + r, 64);

    // O lane layout: row t = quad*4+r (+mi*16), col d = li (+dj*16)
    #pragma unroll
    for (int mi = 0; mi < 2; ++mi)
        #pragma unroll
        for (int dj = 0; dj < 4; ++dj)
            #pragma unroll
            for (int r = 0; r < 4; ++r) {
                int t = qt0w + mi*16 + quad*4 + r;
                ao16[((size_t)(b*TT + t))*DIM + h*HD + dj*16 + li] =
                    f2bf(oacc[mi][dj][r] * inv[mi][r]);
            }
}

extern "C" void kernel_launch(void* const* d_in, const int* in_sizes, int n_in,
                              void* d_out, int out_size, void* d_ws, size_t ws_size,
                              hipStream_t stream)
{
    const float* x     = (const float*)d_in[0];   // [4,2048,512] f32
    const float* Wqkv  = (const float*)d_in[1];   // [512,1024]  f32
    const float* Wproj = (const float*)d_in[2];   // [512,512]   f32
    const float* bproj = (const float*)d_in[3];   // [512]       f32
    float* out = (float*)d_out;                   // [4,2048,512] f32

    char* ws = (char*)d_ws;
    const size_t MB = 1024*1024;
    u16*   q16  = (u16*)(ws);                          // 8 MB  [b,h,t,d] bf16
    u16*   vt16 = (u16*)(ws + 8*MB);                   // 8 MB  [b,h,d,t] bf16
    u16*   ao16 = (u16*)(ws + 16*MB);                  // 8 MB  [b,t,dim] bf16
    u16*   x16  = (u16*)(ws + 24*MB);                  // 8 MB  [b,t,dim] bf16
    u16*   Wtq  = (u16*)(ws + 32*MB);                  // 1 MB  [1024][512]
    u16*   Wtp  = (u16*)(ws + 33*MB);                  // 0.5MB [512][512]
    float* qsq  = (float*)(ws + 34*MB);                // 256 KB (16B aligned)
    float* asq  = (float*)(ws + 34*MB + 262144);       // 128 B
    u32* bmaxsq = (u32*)(ws + 34*MB + 262144 + 128);   // 16 B

    (void)in_sizes; (void)n_in; (void)out_size; (void)ws_size;

    hipMemsetAsync(ws + 34*MB + 262144, 0, 144, stream);

    prep_kernel<<<1024, 256, 0, stream>>>(x, x16, bmaxsq, Wqkv, Wtq, Wproj, Wtp);

    qkv_mfma<<<64*8, 256, 0, stream>>>(x16, Wtq, q16, vt16);

    qsq_kernel<<<BH*8, 256, 0, stream>>>(q16, qsq, asq);

    attn_kernel<<<BH*16, 256, 0, stream>>>(q16, vt16, qsq, asq, bmaxsq, ao16);

    proj_mfma<<<64*4, 256, 0, stream>>>(ao16, Wtp, bproj, out);
}

// Round 10
// 212.287 us; speedup vs baseline: 1.7958x; 1.2161x over previous
//
#include <hip/hip_runtime.h>
#include <hip/hip_bf16.h>

#define BB 4
#define TT 2048
#define DIM 512
#define NH 8
#define HD 64
#define NROW (BB*TT)   // 8192
#define BH (BB*NH)     // 32

typedef unsigned short u16;
typedef unsigned int u32;
typedef __attribute__((ext_vector_type(8))) short bf16x8;   // 8 bf16 = 4 VGPRs
typedef __attribute__((ext_vector_type(8))) unsigned short u16x8;
typedef __attribute__((ext_vector_type(4))) float f32x4;
typedef __attribute__((ext_vector_type(4))) unsigned short u16x4;

static __device__ __forceinline__ float bf2f(u16 u) {
    return __uint_as_float(((u32)u) << 16);
}
static __device__ __forceinline__ u16 f2bf(float f) {
    u32 u = __float_as_uint(f);
    u32 r = (u + 0x7FFFu + ((u >> 16) & 1u)) >> 16;
    return (u16)r;
}
// round-half-up pack of two f32 -> two bf16 in one u32
static __device__ __forceinline__ u32 pk2bf(float a, float b) {
    u32 ua = (__float_as_uint(a) + 0x8000u) >> 16;
    u32 ub = (__float_as_uint(b) + 0x8000u) & 0xFFFF0000u;
    return ua | ub;
}

// ---------------- prep: fused convert_x (blocks 0..255) + W transposes
__global__ __launch_bounds__(256) void prep_kernel(
    const float* __restrict__ x, u16* __restrict__ x16, u32* __restrict__ bmaxsq,
    const float* __restrict__ Wqkv, u16* __restrict__ Wtq,
    const float* __restrict__ Wproj, u16* __restrict__ Wtp)
{
    const int bid = blockIdx.x;
    const int tid = threadIdx.x;
    __shared__ u16 t[32][33];
    __shared__ float red[4];

    if (bid < 256) {
        const int row = bid * 32 + (tid >> 3);
        const int b = (bid * 32) >> 11;
        const float* xr = x   + (size_t)row * DIM + (tid & 7) * 64;
        u16*        xo  = x16 + (size_t)row * DIM + (tid & 7) * 64;
        float s = 0.0f;
        #pragma unroll
        for (int j = 0; j < 8; ++j) {
            float4 a = *(const float4*)(xr + j*8);
            float4 c = *(const float4*)(xr + j*8 + 4);
            s += a.x*a.x + a.y*a.y + a.z*a.z + a.w*a.w;
            s += c.x*c.x + c.y*c.y + c.z*c.z + c.w*c.w;
            u16x8 pk;
            pk[0]=f2bf(a.x); pk[1]=f2bf(a.y); pk[2]=f2bf(a.z); pk[3]=f2bf(a.w);
            pk[4]=f2bf(c.x); pk[5]=f2bf(c.y); pk[6]=f2bf(c.z); pk[7]=f2bf(c.w);
            *(u16x8*)(xo + j*8) = pk;
        }
        #pragma unroll
        for (int off = 1; off < 8; off <<= 1) s += __shfl_xor(s, off, 64);
        float m = s;
        #pragma unroll
        for (int off = 8; off < 64; off <<= 1) m = fmaxf(m, __shfl_xor(m, off, 64));
        if ((tid & 63) == 0) red[tid >> 6] = m;
        __syncthreads();
        if (tid == 0) {
            float mx = fmaxf(fmaxf(red[0], red[1]), fmaxf(red[2], red[3]));
            atomicMax(&bmaxsq[b], __float_as_uint(mx));
        }
    } else {
        const float* in; u16* outp; int K, N, tb;
        if (bid < 768) { in = Wqkv; outp = Wtq; K = 512; N = 1024; tb = bid - 256; }
        else           { in = Wproj; outp = Wtp; K = 512; N = 512;  tb = bid - 768; }
        const int ntiles = N >> 5;
        const int bx = tb % ntiles, by = tb / ntiles;
        const int n0 = bx * 32, k0 = by * 32;
        const int tx = tid & 31, ty = tid >> 5;
        #pragma unroll
        for (int i = 0; i < 32; i += 8)
            t[ty + i][tx] = f2bf(in[(size_t)(k0 + ty + i) * N + n0 + tx]);
        __syncthreads();
        #pragma unroll
        for (int i = 0; i < 32; i += 8)
            outp[(size_t)(n0 + ty + i) * K + k0 + tx] = t[tx][ty + i];
    }
}

// ---------------- MFMA GEMM: qkv = x16 @ Wqkv (via Wt [1024][512] bf16)
#define LDG 72
__global__ __launch_bounds__(256) void qkv_mfma(
    const u16* __restrict__ x16, const u16* __restrict__ Wt,
    u16* __restrict__ q16, u16* __restrict__ vt16)
{
    const int tid = threadIdx.x, lane = tid & 63, w = tid >> 6;
    const int li = lane & 15, quad = lane >> 4;
    const int mb = blockIdx.x >> 3, nb = blockIdx.x & 7;   // 64 x 8
    const int row0 = mb * 128, n0 = nb * 128;
    const int b = row0 >> 11;
    const int wm = w >> 1, wn = w & 1;

    __shared__ __align__(16) u16 as[128 * LDG];
    __shared__ __align__(16) u16 bs[128 * LDG];

    f32x4 acc[4][4];
    #pragma unroll
    for (int mi = 0; mi < 4; ++mi)
        #pragma unroll
        for (int ni = 0; ni < 4; ++ni) acc[mi][ni] = f32x4{0.f,0.f,0.f,0.f};

    for (int k0 = 0; k0 < DIM; k0 += 64) {
        __syncthreads();
        #pragma unroll
        for (int it = 0; it < 4; ++it) {
            int id = it * 256 + tid;
            int r = id >> 3, c = id & 7;
            *(bf16x8*)&as[r*LDG + c*8] =
                *(const bf16x8*)(x16 + (size_t)(row0 + r)*DIM + k0 + c*8);
            *(bf16x8*)&bs[r*LDG + c*8] =
                *(const bf16x8*)(Wt  + (size_t)(n0  + r)*DIM + k0 + c*8);
        }
        __syncthreads();

        bf16x8 af[4][2], bfr[4][2];
        #pragma unroll
        for (int mi = 0; mi < 4; ++mi) {
            const u16* p = &as[(wm*64 + mi*16 + li)*LDG + quad*8];
            af[mi][0] = *(const bf16x8*)p;
            af[mi][1] = *(const bf16x8*)(p + 32);
        }
        #pragma unroll
        for (int ni = 0; ni < 4; ++ni) {
            const u16* p = &bs[(wn*64 + ni*16 + li)*LDG + quad*8];
            bfr[ni][0] = *(const bf16x8*)p;
            bfr[ni][1] = *(const bf16x8*)(p + 32);
        }
        #pragma unroll
        for (int mi = 0; mi < 4; ++mi)
            #pragma unroll
            for (int ni = 0; ni < 4; ++ni) {
                acc[mi][ni] = __builtin_amdgcn_mfma_f32_16x16x32_bf16(
                    af[mi][0], bfr[ni][0], acc[mi][ni], 0, 0, 0);
                acc[mi][ni] = __builtin_amdgcn_mfma_f32_16x16x32_bf16(
                    af[mi][1], bfr[ni][1], acc[mi][ni], 0, 0, 0);
            }
    }

    const int h = li & 7;
    const bool isv = ((li >> 3) & 1) != 0;
    #pragma unroll
    for (int ni = 0; ni < 4; ++ni) {
        int col0 = n0 + wn*64 + ni*16;
        int d = col0 >> 4;
        #pragma unroll
        for (int mi = 0; mi < 4; ++mi) {
            int t0 = (row0 & (TT-1)) + wm*64 + mi*16 + quad*4;
            if (!isv) {
                u16* dst = q16 + ((size_t)(b*NH + h)*TT + t0)*HD + d;
                #pragma unroll
                for (int r = 0; r < 4; ++r)
                    dst[(size_t)r * HD] = f2bf(acc[mi][ni][r]);
            } else {
                u16x4 pk;
                pk.x = f2bf(acc[mi][ni][0]); pk.y = f2bf(acc[mi][ni][1]);
                pk.z = f2bf(acc[mi][ni][2]); pk.w = f2bf(acc[mi][ni][3]);
                *(u16x4*)(vt16 + ((size_t)(b*NH + h)*HD + d)*TT + t0) = pk;
            }
        }
    }
}

// ---------------- MFMA GEMM: out(f32) = ao16 @ Wproj + bias(f32)
__global__ __launch_bounds__(256) void proj_mfma(
    const u16* __restrict__ ao16, const u16* __restrict__ Wt,
    const float* __restrict__ bp, float* __restrict__ out)
{
    const int tid = threadIdx.x, lane = tid & 63, w = tid >> 6;
    const int li = lane & 15, quad = lane >> 4;
    const int mb = blockIdx.x >> 2, nb = blockIdx.x & 3;   // 64 x 4
    const int row0 = mb * 128, n0 = nb * 128;
    const int wm = w >> 1, wn = w & 1;

    __shared__ __align__(16) u16 as[128 * LDG];
    __shared__ __align__(16) u16 bs[128 * LDG];

    f32x4 acc[4][4];
    #pragma unroll
    for (int mi = 0; mi < 4; ++mi)
        #pragma unroll
        for (int ni = 0; ni < 4; ++ni) acc[mi][ni] = f32x4{0.f,0.f,0.f,0.f};

    for (int k0 = 0; k0 < DIM; k0 += 64) {
        __syncthreads();
        #pragma unroll
        for (int it = 0; it < 4; ++it) {
            int id = it * 256 + tid;
            int r = id >> 3, c = id & 7;
            *(bf16x8*)&as[r*LDG + c*8] =
                *(const bf16x8*)(ao16 + (size_t)(row0 + r)*DIM + k0 + c*8);
            *(bf16x8*)&bs[r*LDG + c*8] =
                *(const bf16x8*)(Wt   + (size_t)(n0  + r)*DIM + k0 + c*8);
        }
        __syncthreads();

        bf16x8 af[4][2], bfr[4][2];
        #pragma unroll
        for (int mi = 0; mi < 4; ++mi) {
            const u16* p = &as[(wm*64 + mi*16 + li)*LDG + quad*8];
            af[mi][0] = *(const bf16x8*)p;
            af[mi][1] = *(const bf16x8*)(p + 32);
        }
        #pragma unroll
        for (int ni = 0; ni < 4; ++ni) {
            const u16* p = &bs[(wn*64 + ni*16 + li)*LDG + quad*8];
            bfr[ni][0] = *(const bf16x8*)p;
            bfr[ni][1] = *(const bf16x8*)(p + 32);
        }
        #pragma unroll
        for (int mi = 0; mi < 4; ++mi)
            #pragma unroll
            for (int ni = 0; ni < 4; ++ni) {
                acc[mi][ni] = __builtin_amdgcn_mfma_f32_16x16x32_bf16(
                    af[mi][0], bfr[ni][0], acc[mi][ni], 0, 0, 0);
                acc[mi][ni] = __builtin_amdgcn_mfma_f32_16x16x32_bf16(
                    af[mi][1], bfr[ni][1], acc[mi][ni], 0, 0, 0);
            }
    }

    #pragma unroll
    for (int ni = 0; ni < 4; ++ni) {
        int col = n0 + wn*64 + ni*16 + li;
        float bias = bp[col];
        #pragma unroll
        for (int mi = 0; mi < 4; ++mi) {
            int r0 = row0 + wm*64 + mi*16 + quad*4;
            #pragma unroll
            for (int r = 0; r < 4; ++r)
                out[(size_t)(r0 + r)*DIM + col] = acc[mi][ni][r] + bias;
        }
    }
}

// ---------------- qsq: qsq[b,h,t] = sum_d q^2 ; asq[b,h] via 1 atomic/block
__global__ __launch_bounds__(256) void qsq_kernel(
    const u16* __restrict__ q16, float* __restrict__ qsq, float* __restrict__ asq)
{
    const int tid = threadIdx.x;
    const int bh = blockIdx.x >> 3;
    const int r0 = (blockIdx.x & 7) * 256;
    const u16* qb = q16 + ((size_t)bh * TT + r0) * HD;

    float tot = 0.0f;
    #pragma unroll
    for (int i = 0; i < 8; ++i) {
        int row = i * 32 + (tid >> 3);
        u16x8 v = *(const u16x8*)(qb + (size_t)row * HD + (tid & 7) * 8);
        float s = 0.0f;
        #pragma unroll
        for (int j = 0; j < 8; ++j) { float f = bf2f(v[j]); s += f * f; }
        tot += s;
        #pragma unroll
        for (int off = 1; off < 8; off <<= 1) s += __shfl_xor(s, off, 64);
        if ((tid & 7) == 0) qsq[(size_t)bh * TT + r0 + row] = s;
    }
    __shared__ float red[4];
    #pragma unroll
    for (int off = 32; off > 0; off >>= 1) tot += __shfl_down(tot, off, 64);
    if ((tid & 63) == 0) red[tid >> 6] = tot;
    __syncthreads();
    if (tid == 0) atomicAdd(&asq[bh], red[0] + red[1] + red[2] + red[3]);
}

// ---------------- attention v5: 512-thread blocks (8 waves x 16 q-rows),
// double-buffered K/V staging with register prefetch -> ONE barrier per
// 64-s tile; S^T operand order (b64 P-writes); known-max softmax (exp2).
// LDS 55.3 KB -> 2 blocks/CU -> 16 waves/CU.
#define LDK 72
#define LDP 72
__global__ __launch_bounds__(512) void attn_kernel(
    const u16* __restrict__ q16, const u16* __restrict__ vt16,
    const float* __restrict__ qsq, const float* __restrict__ asq,
    const u32* __restrict__ bmaxsq, u16* __restrict__ ao16)
{
    const int tid = threadIdx.x;
    const int lane = tid & 63, w = tid >> 6;          // 8 waves
    const int li = lane & 15, quad = lane >> 4;
    const int bh = blockIdx.x >> 4;                   // 32
    const int qtile = blockIdx.x & 15;                // 16 tiles x 128 q-rows
    const int b = bh >> 3, h = bh & 7;

    __shared__ __align__(16) u16 ks[2][64 * LDK];     // K tile  [s][d]
    __shared__ __align__(16) u16 vt[2][64 * LDK];     // V^T tile [d][s]
    __shared__ __align__(16) u16 ps[8][16 * LDP];     // per-wave P [t][s]

    const u16* qg = q16  + (size_t)bh * TT * HD;      // [t][d]
    const u16* vg = vt16 + (size_t)bh * HD * TT;      // [d][t]
    const float* qsqg = qsq + (size_t)bh * TT;

    float cf;   // 100 * log2(e) / (a * bmax + eps)
    {
        float a  = sqrtf(asq[bh]);
        float bm = sqrtf(__uint_as_float(bmaxsq[b]));
        cf = (100.0f * 1.44269504089f) / (a * bm + 1e-10f);
    }
    const float c2 = 2.0f * cf;

    const int qt0w = qtile * 128 + w * 16;
    const u16* qr = qg + (size_t)(qt0w + li) * HD + quad * 8;
    bf16x8 a0 = *(const bf16x8*)qr;        // Q B-frag: t-col = li
    bf16x8 a1 = *(const bf16x8*)(qr + 32);
    const float sqt = cf * qsqg[qt0w + li];

    // staging: 512 threads, each 1 chunk of ks + 1 of vt per tile
    const int sr = tid >> 3, sc = tid & 7;
    const u16* kptr = qg + (size_t)sr * HD + sc * 8;  // advance 64*HD per tile
    const u16* vptr = vg + (size_t)sr * TT + sc * 8;  // advance 64 per tile
    const int soff = sr * LDK + sc * 8;

    u16* psw = &ps[w][0];
    float ssum = 0.0f;
    f32x4 oacc[4];
    #pragma unroll
    for (int dj = 0; dj < 4; ++dj) oacc[dj] = f32x4{0.f, 0.f, 0.f, 0.f};

    // preload + write tile 0 into buffer 0
    bf16x8 kreg = *(const bf16x8*)kptr;
    bf16x8 vreg = *(const bf16x8*)vptr;
    *(bf16x8*)&ks[0][soff] = kreg;
    *(bf16x8*)&vt[0][soff] = vreg;
    __syncthreads();

    for (int t = 0; t < TT/64; ++t) {
        const int cur = t & 1;
        const int s0 = t * 64;
        // prefetch next tile into regs (latency hidden under compute)
        if (t + 1 < TT/64) {
            kreg = *(const bf16x8*)(kptr + (size_t)(t+1) * 64 * HD);
            vreg = *(const bf16x8*)(vptr + (t+1) * 64);
        }

        // ---- S^T = K Q^T : lane holds s-rows cj*16+quad*4+r, t-col li
        #pragma unroll
        for (int cj = 0; cj < 4; ++cj) {
            const u16* kr = &ks[cur][(cj*16 + li)*LDK + quad*8];
            bf16x8 k0 = *(const bf16x8*)kr;
            bf16x8 k1 = *(const bf16x8*)(kr + 32);
            f32x4 acc = f32x4{0.f, 0.f, 0.f, 0.f};
            acc = __builtin_amdgcn_mfma_f32_16x16x32_bf16(k0, a0, acc, 0, 0, 0);
            acc = __builtin_amdgcn_mfma_f32_16x16x32_bf16(k1, a1, acc, 0, 0, 0);
            f32x4 q4 = *(const f32x4*)(qsqg + s0 + cj*16 + quad*4);
            float p0 = exp2f(c2*acc[0] - fmaf(cf, q4[0], sqt));
            float p1 = exp2f(c2*acc[1] - fmaf(cf, q4[1], sqt));
            float p2 = exp2f(c2*acc[2] - fmaf(cf, q4[2], sqt));
            float p3 = exp2f(c2*acc[3] - fmaf(cf, q4[3], sqt));
            ssum += (p0 + p1) + (p2 + p3);
            uint2 pk;
            pk.x = pk2bf(p0, p1);
            pk.y = pk2bf(p2, p3);
            *(uint2*)&psw[li*LDP + cj*16 + quad*4] = pk;
        }

        // ---- O += P V : A = P rows t (wave-private), B = V^T rows d
        #pragma unroll
        for (int kj = 0; kj < 2; ++kj) {
            bf16x8 ap = *(const bf16x8*)&psw[li*LDP + kj*32 + quad*8];
            #pragma unroll
            for (int dj = 0; dj < 4; ++dj) {
                bf16x8 bv = *(const bf16x8*)&vt[cur][(dj*16 + li)*LDK + kj*32 + quad*8];
                oacc[dj] = __builtin_amdgcn_mfma_f32_16x16x32_bf16(
                    ap, bv, oacc[dj], 0, 0, 0);
            }
        }

        // write prefetched tile into the other buffer; one barrier covers
        // both hazards (our reads of cur done; peers' writes of cur^1 done)
        if (t + 1 < TT/64) {
            *(bf16x8*)&ks[cur ^ 1][soff] = kreg;
            *(bf16x8*)&vt[cur ^ 1][soff] = vreg;
        }
        __syncthreads();
    }

    // denom: lane li holds t-col; reduce the 4 quad-partials, redistribute
    ssum += __shfl_xor(ssum, 16, 64);
    ssum += __shfl_xor(ssum, 32, 64);
    float inv[4];
    #pragma unroll
    for (int r = 0; r < 4; ++r)
        inv[r] = 1.0f / __shfl(ssum, quad*4 + r, 64);

    // O lane layout: row t = quad*4+r, col d = li (+dj*16)
    #pragma unroll
    for (int dj = 0; dj < 4; ++dj)
        #pragma unroll
        for (int r = 0; r < 4; ++r) {
            int t = qt0w + quad*4 + r;
            ao16[((size_t)(b*TT + t))*DIM + h*HD + dj*16 + li] =
                f2bf(oacc[dj][r] * inv[r]);
        }
}

extern "C" void kernel_launch(void* const* d_in, const int* in_sizes, int n_in,
                              void* d_out, int out_size, void* d_ws, size_t ws_size,
                              hipStream_t stream)
{
    const float* x     = (const float*)d_in[0];   // [4,2048,512] f32
    const float* Wqkv  = (const float*)d_in[1];   // [512,1024]  f32
    const float* Wproj = (const float*)d_in[2];   // [512,512]   f32
    const float* bproj = (const float*)d_in[3];   // [512]       f32
    float* out = (float*)d_out;                   // [4,2048,512] f32

    char* ws = (char*)d_ws;
    const size_t MB = 1024*1024;
    u16*   q16  = (u16*)(ws);                          // 8 MB  [b,h,t,d] bf16
    u16*   vt16 = (u16*)(ws + 8*MB);                   // 8 MB  [b,h,d,t] bf16
    u16*   ao16 = (u16*)(ws + 16*MB);                  // 8 MB  [b,t,dim] bf16
    u16*   x16  = (u16*)(ws + 24*MB);                  // 8 MB  [b,t,dim] bf16
    u16*   Wtq  = (u16*)(ws + 32*MB);                  // 1 MB  [1024][512]
    u16*   Wtp  = (u16*)(ws + 33*MB);                  // 0.5MB [512][512]
    float* qsq  = (float*)(ws + 34*MB);                // 256 KB (16B aligned)
    float* asq  = (float*)(ws + 34*MB + 262144);       // 128 B
    u32* bmaxsq = (u32*)(ws + 34*MB + 262144 + 128);   // 16 B

    (void)in_sizes; (void)n_in; (void)out_size; (void)ws_size;

    hipMemsetAsync(ws + 34*MB + 262144, 0, 144, stream);

    prep_kernel<<<1024, 256, 0, stream>>>(x, x16, bmaxsq, Wqkv, Wtq, Wproj, Wtp);

    qkv_mfma<<<64*8, 256, 0, stream>>>(x16, Wtq, q16, vt16);

    qsq_kernel<<<BH*8, 256, 0, stream>>>(q16, qsq, asq);

    attn_kernel<<<BH*16, 512, 0, stream>>>(q16, vt16, qsq, asq, bmaxsq, ao16);

    proj_mfma<<<64*4, 256, 0, stream>>>(ao16, Wtp, bproj, out);
}

// Round 11
// 206.793 us; speedup vs baseline: 1.8435x; 1.0266x over previous
//
#include <hip/hip_runtime.h>
#include <hip/hip_bf16.h>

#define BB 4
#define TT 2048
#define DIM 512
#define NH 8
#define HD 64
#define NROW (BB*TT)   // 8192
#define BH (BB*NH)     // 32

typedef unsigned short u16;
typedef unsigned int u32;
typedef __attribute__((ext_vector_type(8))) short bf16x8;   // 8 bf16 = 4 VGPRs
typedef __attribute__((ext_vector_type(8))) unsigned short u16x8;
typedef __attribute__((ext_vector_type(4))) float f32x4;
typedef __attribute__((ext_vector_type(4))) unsigned short u16x4;

static __device__ __forceinline__ float bf2f(u16 u) {
    return __uint_as_float(((u32)u) << 16);
}
static __device__ __forceinline__ u16 f2bf(float f) {
    u32 u = __float_as_uint(f);
    u32 r = (u + 0x7FFFu + ((u >> 16) & 1u)) >> 16;
    return (u16)r;
}
// packed f32x2 -> bf16x2 (v_cvt_pk_bf16_f32 on gfx950)
static __device__ __forceinline__ u32 cvtpk(float a, float b) {
    union { __hip_bfloat162 h2; u32 u; } cv;
    cv.h2 = __float22bfloat162_rn(make_float2(a, b));
    return cv.u;
}

// ---------------- prep: fused convert_x (blocks 0..255) + W transposes
__global__ __launch_bounds__(256) void prep_kernel(
    const float* __restrict__ x, u16* __restrict__ x16, u32* __restrict__ bmaxsq,
    const float* __restrict__ Wqkv, u16* __restrict__ Wtq,
    const float* __restrict__ Wproj, u16* __restrict__ Wtp)
{
    const int bid = blockIdx.x;
    const int tid = threadIdx.x;
    __shared__ u16 t[32][33];
    __shared__ float red[4];

    if (bid < 256) {
        const int row = bid * 32 + (tid >> 3);
        const int b = (bid * 32) >> 11;
        const float* xr = x   + (size_t)row * DIM + (tid & 7) * 64;
        u16*        xo  = x16 + (size_t)row * DIM + (tid & 7) * 64;
        float s = 0.0f;
        #pragma unroll
        for (int j = 0; j < 8; ++j) {
            float4 a = *(const float4*)(xr + j*8);
            float4 c = *(const float4*)(xr + j*8 + 4);
            s += a.x*a.x + a.y*a.y + a.z*a.z + a.w*a.w;
            s += c.x*c.x + c.y*c.y + c.z*c.z + c.w*c.w;
            u16x8 pk;
            pk[0]=f2bf(a.x); pk[1]=f2bf(a.y); pk[2]=f2bf(a.z); pk[3]=f2bf(a.w);
            pk[4]=f2bf(c.x); pk[5]=f2bf(c.y); pk[6]=f2bf(c.z); pk[7]=f2bf(c.w);
            *(u16x8*)(xo + j*8) = pk;
        }
        #pragma unroll
        for (int off = 1; off < 8; off <<= 1) s += __shfl_xor(s, off, 64);
        float m = s;
        #pragma unroll
        for (int off = 8; off < 64; off <<= 1) m = fmaxf(m, __shfl_xor(m, off, 64));
        if ((tid & 63) == 0) red[tid >> 6] = m;
        __syncthreads();
        if (tid == 0) {
            float mx = fmaxf(fmaxf(red[0], red[1]), fmaxf(red[2], red[3]));
            atomicMax(&bmaxsq[b], __float_as_uint(mx));
        }
    } else {
        const float* in; u16* outp; int K, N, tb;
        if (bid < 768) { in = Wqkv; outp = Wtq; K = 512; N = 1024; tb = bid - 256; }
        else           { in = Wproj; outp = Wtp; K = 512; N = 512;  tb = bid - 768; }
        const int ntiles = N >> 5;
        const int bx = tb % ntiles, by = tb / ntiles;
        const int n0 = bx * 32, k0 = by * 32;
        const int tx = tid & 31, ty = tid >> 5;
        #pragma unroll
        for (int i = 0; i < 32; i += 8)
            t[ty + i][tx] = f2bf(in[(size_t)(k0 + ty + i) * N + n0 + tx]);
        __syncthreads();
        #pragma unroll
        for (int i = 0; i < 32; i += 8)
            outp[(size_t)(n0 + ty + i) * K + k0 + tx] = t[tx][ty + i];
    }
}

// ---------------- MFMA GEMM: qkv = x16 @ Wqkv (via Wt [1024][512] bf16)
#define LDG 72
__global__ __launch_bounds__(256) void qkv_mfma(
    const u16* __restrict__ x16, const u16* __restrict__ Wt,
    u16* __restrict__ q16, u16* __restrict__ vt16)
{
    const int tid = threadIdx.x, lane = tid & 63, w = tid >> 6;
    const int li = lane & 15, quad = lane >> 4;
    const int mb = blockIdx.x >> 3, nb = blockIdx.x & 7;   // 64 x 8
    const int row0 = mb * 128, n0 = nb * 128;
    const int b = row0 >> 11;
    const int wm = w >> 1, wn = w & 1;

    __shared__ __align__(16) u16 as[128 * LDG];
    __shared__ __align__(16) u16 bs[128 * LDG];

    f32x4 acc[4][4];
    #pragma unroll
    for (int mi = 0; mi < 4; ++mi)
        #pragma unroll
        for (int ni = 0; ni < 4; ++ni) acc[mi][ni] = f32x4{0.f,0.f,0.f,0.f};

    for (int k0 = 0; k0 < DIM; k0 += 64) {
        __syncthreads();
        #pragma unroll
        for (int it = 0; it < 4; ++it) {
            int id = it * 256 + tid;
            int r = id >> 3, c = id & 7;
            *(bf16x8*)&as[r*LDG + c*8] =
                *(const bf16x8*)(x16 + (size_t)(row0 + r)*DIM + k0 + c*8);
            *(bf16x8*)&bs[r*LDG + c*8] =
                *(const bf16x8*)(Wt  + (size_t)(n0  + r)*DIM + k0 + c*8);
        }
        __syncthreads();

        bf16x8 af[4][2], bfr[4][2];
        #pragma unroll
        for (int mi = 0; mi < 4; ++mi) {
            const u16* p = &as[(wm*64 + mi*16 + li)*LDG + quad*8];
            af[mi][0] = *(const bf16x8*)p;
            af[mi][1] = *(const bf16x8*)(p + 32);
        }
        #pragma unroll
        for (int ni = 0; ni < 4; ++ni) {
            const u16* p = &bs[(wn*64 + ni*16 + li)*LDG + quad*8];
            bfr[ni][0] = *(const bf16x8*)p;
            bfr[ni][1] = *(const bf16x8*)(p + 32);
        }
        #pragma unroll
        for (int mi = 0; mi < 4; ++mi)
            #pragma unroll
            for (int ni = 0; ni < 4; ++ni) {
                acc[mi][ni] = __builtin_amdgcn_mfma_f32_16x16x32_bf16(
                    af[mi][0], bfr[ni][0], acc[mi][ni], 0, 0, 0);
                acc[mi][ni] = __builtin_amdgcn_mfma_f32_16x16x32_bf16(
                    af[mi][1], bfr[ni][1], acc[mi][ni], 0, 0, 0);
            }
    }

    const int h = li & 7;
    const bool isv = ((li >> 3) & 1) != 0;
    #pragma unroll
    for (int ni = 0; ni < 4; ++ni) {
        int col0 = n0 + wn*64 + ni*16;
        int d = col0 >> 4;
        #pragma unroll
        for (int mi = 0; mi < 4; ++mi) {
            int t0 = (row0 & (TT-1)) + wm*64 + mi*16 + quad*4;
            if (!isv) {
                u16* dst = q16 + ((size_t)(b*NH + h)*TT + t0)*HD + d;
                #pragma unroll
                for (int r = 0; r < 4; ++r)
                    dst[(size_t)r * HD] = f2bf(acc[mi][ni][r]);
            } else {
                u16x4 pk;
                pk.x = f2bf(acc[mi][ni][0]); pk.y = f2bf(acc[mi][ni][1]);
                pk.z = f2bf(acc[mi][ni][2]); pk.w = f2bf(acc[mi][ni][3]);
                *(u16x4*)(vt16 + ((size_t)(b*NH + h)*HD + d)*TT + t0) = pk;
            }
        }
    }
}

// ---------------- MFMA GEMM: out(f32) = ao16 @ Wproj + bias(f32)
__global__ __launch_bounds__(256) void proj_mfma(
    const u16* __restrict__ ao16, const u16* __restrict__ Wt,
    const float* __restrict__ bp, float* __restrict__ out)
{
    const int tid = threadIdx.x, lane = tid & 63, w = tid >> 6;
    const int li = lane & 15, quad = lane >> 4;
    const int mb = blockIdx.x >> 2, nb = blockIdx.x & 3;   // 64 x 4
    const int row0 = mb * 128, n0 = nb * 128;
    const int wm = w >> 1, wn = w & 1;

    __shared__ __align__(16) u16 as[128 * LDG];
    __shared__ __align__(16) u16 bs[128 * LDG];

    f32x4 acc[4][4];
    #pragma unroll
    for (int mi = 0; mi < 4; ++mi)
        #pragma unroll
        for (int ni = 0; ni < 4; ++ni) acc[mi][ni] = f32x4{0.f,0.f,0.f,0.f};

    for (int k0 = 0; k0 < DIM; k0 += 64) {
        __syncthreads();
        #pragma unroll
        for (int it = 0; it < 4; ++it) {
            int id = it * 256 + tid;
            int r = id >> 3, c = id & 7;
            *(bf16x8*)&as[r*LDG + c*8] =
                *(const bf16x8*)(ao16 + (size_t)(row0 + r)*DIM + k0 + c*8);
            *(bf16x8*)&bs[r*LDG + c*8] =
                *(const bf16x8*)(Wt   + (size_t)(n0  + r)*DIM + k0 + c*8);
        }
        __syncthreads();

        bf16x8 af[4][2], bfr[4][2];
        #pragma unroll
        for (int mi = 0; mi < 4; ++mi) {
            const u16* p = &as[(wm*64 + mi*16 + li)*LDG + quad*8];
            af[mi][0] = *(const bf16x8*)p;
            af[mi][1] = *(const bf16x8*)(p + 32);
        }
        #pragma unroll
        for (int ni = 0; ni < 4; ++ni) {
            const u16* p = &bs[(wn*64 + ni*16 + li)*LDG + quad*8];
            bfr[ni][0] = *(const bf16x8*)p;
            bfr[ni][1] = *(const bf16x8*)(p + 32);
        }
        #pragma unroll
        for (int mi = 0; mi < 4; ++mi)
            #pragma unroll
            for (int ni = 0; ni < 4; ++ni) {
                acc[mi][ni] = __builtin_amdgcn_mfma_f32_16x16x32_bf16(
                    af[mi][0], bfr[ni][0], acc[mi][ni], 0, 0, 0);
                acc[mi][ni] = __builtin_amdgcn_mfma_f32_16x16x32_bf16(
                    af[mi][1], bfr[ni][1], acc[mi][ni], 0, 0, 0);
            }
    }

    #pragma unroll
    for (int ni = 0; ni < 4; ++ni) {
        int col = n0 + wn*64 + ni*16 + li;
        float bias = bp[col];
        #pragma unroll
        for (int mi = 0; mi < 4; ++mi) {
            int r0 = row0 + wm*64 + mi*16 + quad*4;
            #pragma unroll
            for (int r = 0; r < 4; ++r)
                out[(size_t)(r0 + r)*DIM + col] = acc[mi][ni][r] + bias;
        }
    }
}

// ---------------- qsq: qsq[b,h,t] = sum_d q^2 ; asq[b,h] via 1 atomic/block
__global__ __launch_bounds__(256) void qsq_kernel(
    const u16* __restrict__ q16, float* __restrict__ qsq, float* __restrict__ asq)
{
    const int tid = threadIdx.x;
    const int bh = blockIdx.x >> 3;
    const int r0 = (blockIdx.x & 7) * 256;
    const u16* qb = q16 + ((size_t)bh * TT + r0) * HD;

    float tot = 0.0f;
    #pragma unroll
    for (int i = 0; i < 8; ++i) {
        int row = i * 32 + (tid >> 3);
        u16x8 v = *(const u16x8*)(qb + (size_t)row * HD + (tid & 7) * 8);
        float s = 0.0f;
        #pragma unroll
        for (int j = 0; j < 8; ++j) { float f = bf2f(v[j]); s += f * f; }
        tot += s;
        #pragma unroll
        for (int off = 1; off < 8; off <<= 1) s += __shfl_xor(s, off, 64);
        if ((tid & 7) == 0) qsq[(size_t)bh * TT + r0 + row] = s;
    }
    __shared__ float red[4];
    #pragma unroll
    for (int off = 32; off > 0; off >>= 1) tot += __shfl_down(tot, off, 64);
    if ((tid & 63) == 0) red[tid >> 6] = tot;
    __syncthreads();
    if (tid == 0) atomicAdd(&asq[bh], red[0] + red[1] + red[2] + red[3]);
}

// ---------------- attention v6: v5 structure + VALU surgery:
// native v_exp_f32 (__builtin_amdgcn_exp2f), packed bf16 cvt
// (v_cvt_pk_bf16_f32), s-loop unrolled x2 with FIXED buffer pointers so
// all LDS frag offsets fold to immediates. One barrier per 64-s tile.
#define LDK 72
#define LDP 72
__global__ __launch_bounds__(512) void attn_kernel(
    const u16* __restrict__ q16, const u16* __restrict__ vt16,
    const float* __restrict__ qsq, const float* __restrict__ asq,
    const u32* __restrict__ bmaxsq, u16* __restrict__ ao16)
{
    const int tid = threadIdx.x;
    const int lane = tid & 63, w = tid >> 6;          // 8 waves
    const int li = lane & 15, quad = lane >> 4;
    const int bh = blockIdx.x >> 4;                   // 32
    const int qtile = blockIdx.x & 15;                // 16 tiles x 128 q-rows
    const int b = bh >> 3, h = bh & 7;

    __shared__ __align__(16) u16 ks0[64 * LDK];       // K tile buf0 [s][d]
    __shared__ __align__(16) u16 ks1[64 * LDK];       // K tile buf1
    __shared__ __align__(16) u16 vt0[64 * LDK];       // V^T tile buf0 [d][s]
    __shared__ __align__(16) u16 vt1[64 * LDK];       // V^T tile buf1
    __shared__ __align__(16) u16 ps[8][16 * LDP];     // per-wave P [t][s]

    const u16* qg = q16  + (size_t)bh * TT * HD;      // [t][d]
    const u16* vg = vt16 + (size_t)bh * HD * TT;      // [d][t]
    const float* qsqg = qsq + (size_t)bh * TT;

    float cf;   // 100 * log2(e) / (a * bmax + eps)
    {
        float a  = sqrtf(asq[bh]);
        float bm = sqrtf(__uint_as_float(bmaxsq[b]));
        cf = (100.0f * 1.44269504089f) / (a * bm + 1e-10f);
    }
    const float c2 = 2.0f * cf;

    const int qt0w = qtile * 128 + w * 16;
    const u16* qr = qg + (size_t)(qt0w + li) * HD + quad * 8;
    bf16x8 a0 = *(const bf16x8*)qr;        // Q B-frag: t-col = li
    bf16x8 a1 = *(const bf16x8*)(qr + 32);
    const float sqt = cf * qsqg[qt0w + li];

    // staging: 512 threads, each 1 chunk of ks + 1 of vt per tile
    const int sr = tid >> 3, sc = tid & 7;
    const u16* kptr = qg + (size_t)sr * HD + sc * 8;  // +64*HD per tile
    const u16* vptr = vg + (size_t)sr * TT + sc * 8;  // +64 per tile
    const int soff = sr * LDK + sc * 8;

    u16* psw = &ps[w][0];
    float ssum = 0.0f;
    f32x4 oacc[4];
    #pragma unroll
    for (int dj = 0; dj < 4; ++dj) oacc[dj] = f32x4{0.f, 0.f, 0.f, 0.f};

    // per-tile compute against a fixed buffer pair (all offsets immediate)
    auto tile_compute = [&](const u16* __restrict__ ksb,
                            const u16* __restrict__ vtb, int s0) {
        #pragma unroll
        for (int cj = 0; cj < 4; ++cj) {
            const u16* kr = ksb + (cj*16 + li)*LDK + quad*8;
            bf16x8 k0 = *(const bf16x8*)kr;
            bf16x8 k1 = *(const bf16x8*)(kr + 32);
            f32x4 acc = f32x4{0.f, 0.f, 0.f, 0.f};
            acc = __builtin_amdgcn_mfma_f32_16x16x32_bf16(k0, a0, acc, 0, 0, 0);
            acc = __builtin_amdgcn_mfma_f32_16x16x32_bf16(k1, a1, acc, 0, 0, 0);
            f32x4 q4 = *(const f32x4*)(qsqg + s0 + cj*16 + quad*4);
            float p0 = __builtin_amdgcn_exp2f(fmaf(c2, acc[0], -fmaf(cf, q4[0], sqt)));
            float p1 = __builtin_amdgcn_exp2f(fmaf(c2, acc[1], -fmaf(cf, q4[1], sqt)));
            float p2 = __builtin_amdgcn_exp2f(fmaf(c2, acc[2], -fmaf(cf, q4[2], sqt)));
            float p3 = __builtin_amdgcn_exp2f(fmaf(c2, acc[3], -fmaf(cf, q4[3], sqt)));
            ssum += (p0 + p1) + (p2 + p3);
            uint2 pk;
            pk.x = cvtpk(p0, p1);
            pk.y = cvtpk(p2, p3);
            *(uint2*)&psw[li*LDP + cj*16 + quad*4] = pk;
        }
        #pragma unroll
        for (int kj = 0; kj < 2; ++kj) {
            bf16x8 ap = *(const bf16x8*)&psw[li*LDP + kj*32 + quad*8];
            #pragma unroll
            for (int dj = 0; dj < 4; ++dj) {
                bf16x8 bv = *(const bf16x8*)(vtb + (dj*16 + li)*LDK + kj*32 + quad*8);
                oacc[dj] = __builtin_amdgcn_mfma_f32_16x16x32_bf16(
                    ap, bv, oacc[dj], 0, 0, 0);
            }
        }
    };

    // preload tile 0 into buf0
    bf16x8 kreg = *(const bf16x8*)kptr;
    bf16x8 vreg = *(const bf16x8*)vptr;
    *(bf16x8*)(ks0 + soff) = kreg;
    *(bf16x8*)(vt0 + soff) = vreg;
    __syncthreads();

    for (int t2 = 0; t2 < 16; ++t2) {
        const int t = 2 * t2;
        // prefetch odd tile (t+1 <= 31 always)
        kreg = *(const bf16x8*)(kptr + (size_t)(t+1) * 64 * HD);
        vreg = *(const bf16x8*)(vptr + (t+1) * 64);
        tile_compute(ks0, vt0, t * 64);
        *(bf16x8*)(ks1 + soff) = kreg;
        *(bf16x8*)(vt1 + soff) = vreg;
        __syncthreads();
        if (t2 < 15) {
            kreg = *(const bf16x8*)(kptr + (size_t)(t+2) * 64 * HD);
            vreg = *(const bf16x8*)(vptr + (t+2) * 64);
        }
        tile_compute(ks1, vt1, (t+1) * 64);
        if (t2 < 15) {
            *(bf16x8*)(ks0 + soff) = kreg;
            *(bf16x8*)(vt0 + soff) = vreg;
            __syncthreads();
        }
    }

    // denom: lane li holds t-col; reduce the 4 quad-partials, redistribute
    ssum += __shfl_xor(ssum, 16, 64);
    ssum += __shfl_xor(ssum, 32, 64);
    float inv[4];
    #pragma unroll
    for (int r = 0; r < 4; ++r)
        inv[r] = 1.0f / __shfl(ssum, quad*4 + r, 64);

    // O lane layout: row t = quad*4+r, col d = li (+dj*16)
    #pragma unroll
    for (int dj = 0; dj < 4; ++dj)
        #pragma unroll
        for (int r = 0; r < 4; ++r) {
            int t = qt0w + quad*4 + r;
            ao16[((size_t)(b*TT + t))*DIM + h*HD + dj*16 + li] =
                f2bf(oacc[dj][r] * inv[r]);
        }
}

extern "C" void kernel_launch(void* const* d_in, const int* in_sizes, int n_in,
                              void* d_out, int out_size, void* d_ws, size_t ws_size,
                              hipStream_t stream)
{
    const float* x     = (const float*)d_in[0];   // [4,2048,512] f32
    const float* Wqkv  = (const float*)d_in[1];   // [512,1024]  f32
    const float* Wproj = (const float*)d_in[2];   // [512,512]   f32
    const float* bproj = (const float*)d_in[3];   // [512]       f32
    float* out = (float*)d_out;                   // [4,2048,512] f32

    char* ws = (char*)d_ws;
    const size_t MB = 1024*1024;
    u16*   q16  = (u16*)(ws);                          // 8 MB  [b,h,t,d] bf16
    u16*   vt16 = (u16*)(ws + 8*MB);                   // 8 MB  [b,h,d,t] bf16
    u16*   ao16 = (u16*)(ws + 16*MB);                  // 8 MB  [b,t,dim] bf16
    u16*   x16  = (u16*)(ws + 24*MB);                  // 8 MB  [b,t,dim] bf16
    u16*   Wtq  = (u16*)(ws + 32*MB);                  // 1 MB  [1024][512]
    u16*   Wtp  = (u16*)(ws + 33*MB);                  // 0.5MB [512][512]
    float* qsq  = (float*)(ws + 34*MB);                // 256 KB (16B aligned)
    float* asq  = (float*)(ws + 34*MB + 262144);       // 128 B
    u32* bmaxsq = (u32*)(ws + 34*MB + 262144 + 128);   // 16 B

    (void)in_sizes; (void)n_in; (void)out_size; (void)ws_size;

    hipMemsetAsync(ws + 34*MB + 262144, 0, 144, stream);

    prep_kernel<<<1024, 256, 0, stream>>>(x, x16, bmaxsq, Wqkv, Wtq, Wproj, Wtp);

    qkv_mfma<<<64*8, 256, 0, stream>>>(x16, Wtq, q16, vt16);

    qsq_kernel<<<BH*8, 256, 0, stream>>>(q16, qsq, asq);

    attn_kernel<<<BH*16, 512, 0, stream>>>(q16, vt16, qsq, asq, bmaxsq, ao16);

    proj_mfma<<<64*4, 256, 0, stream>>>(ao16, Wtp, bproj, out);
}